// Round 3
// baseline (996.007 us; speedup 1.0000x reference)
//
#include <hip/hip_runtime.h>

// Problem constants (fixed by the reference setup)
#define NN      131072       // nodes
#define FF      512          // features
#define EE      2097152      // edges (2^21)
#define DAA     16           // edge attr dim
#define NPOOL   65536        // NN/2 pooled nodes
#define FPOOL   256          // FF/2 pooled features
#define NBUCK   4096         // sort buckets (key >> 20); Poisson(512)/bucket
#define SORT_CAP 2048        // max bucket size (P(>2048) ~ 0; clamped anyway)
#define SCAN_NB 1024         // scan blocks
#define SCAN_EL 2048         // elements per scan block (SCAN_NB*SCAN_EL == EE)

// Output layout (all float32, concatenated flat in return order)
#define OUT_X     0u
#define OUT_ROW   16777216u                    // NPOOL*FPOOL
#define OUT_COL   (OUT_ROW + EE)
#define OUT_ATTR  (OUT_ROW + 2u*EE)
#define OUT_BATCH (OUT_ATTR + EE*DAA)

__device__ __forceinline__ unsigned make_key(const int* ei, unsigned e) {
    unsigned r = ((unsigned)ei[e]) >> 1;
    unsigned c = ((unsigned)ei[EE + e]) >> 1;
    return (r << 16) | c;
}

// K0: zero the 4096-entry histogram (graph-capture-safe, no memset)
__global__ __launch_bounds__(256) void k_zero(unsigned* __restrict__ hist) {
    hist[blockIdx.x * 256u + threadIdx.x] = 0u;
}

// K1: histogram of bucket (top 12 bits of key)
__global__ __launch_bounds__(256) void k_hist(const int* __restrict__ ei,
                                              unsigned* __restrict__ hist) {
    unsigned e = blockIdx.x * 256u + threadIdx.x;
    unsigned key = make_key(ei, e);
    atomicAdd(&hist[key >> 20], 1u);
}

// K2: exclusive scan of 4096 bucket counts -> cursor (single wave)
__global__ void k_bucket_scan(const unsigned* __restrict__ hist,
                              unsigned* __restrict__ cursor) {
    int t = threadIdx.x;              // 0..63
    unsigned local[64];
    unsigned s = 0;
#pragma unroll
    for (int i = 0; i < 64; ++i) { local[i] = hist[t * 64 + i]; s += local[i]; }
    unsigned v = s;
    for (int d = 1; d < 64; d <<= 1) {
        unsigned o = __shfl_up(v, d, 64);
        if (t >= d) v += o;
    }
    unsigned run = v - s;             // exclusive offset
#pragma unroll
    for (int i = 0; i < 64; ++i) { cursor[t * 64 + i] = run; run += local[i]; }
}

// K3: scatter (key, edge_id) into bucket order; cursor[b] ends at bucket end
__global__ __launch_bounds__(256) void k_scatter(const int* __restrict__ ei,
                                                 unsigned* __restrict__ cursor,
                                                 unsigned* __restrict__ keys,
                                                 unsigned* __restrict__ ids) {
    unsigned e = blockIdx.x * 256u + threadIdx.x;
    unsigned key = make_key(ei, e);
    unsigned pos = atomicAdd(&cursor[key >> 20], 1u);
    keys[pos] = key;
    ids[pos]  = e;
}

// K4: per-bucket bitonic sort of packed (key<<32 | id) in LDS.
// Sorting the packed 64-bit value makes the order canonical (deterministic
// despite the atomic scatter) and keeps duplicate keys sorted by edge id,
// which matches JAX segment_sum's summation order.
__global__ __launch_bounds__(256) void k_bsort(const unsigned* __restrict__ cursor,
                                               unsigned* __restrict__ keys,
                                               unsigned* __restrict__ ids) {
    __shared__ unsigned long long lds[SORT_CAP];
    unsigned b = blockIdx.x;
    unsigned start = (b == 0) ? 0u : cursor[b - 1];
    unsigned end   = cursor[b];
    unsigned n = end - start;
    if (n > SORT_CAP) n = SORT_CAP;   // defensive: never overrun LDS
    if (n == 0) return;               // uniform across block
    unsigned P = 1; while (P < n) P <<= 1;
    for (unsigned i = threadIdx.x; i < P; i += 256u) {
        unsigned long long v = ~0ULL;
        if (i < n) v = ((unsigned long long)keys[start + i] << 32) | ids[start + i];
        lds[i] = v;
    }
    __syncthreads();
    for (unsigned k = 2; k <= P; k <<= 1) {
        for (unsigned j = k >> 1; j > 0; j >>= 1) {
            for (unsigned i = threadIdx.x; i < P; i += 256u) {
                unsigned ixj = i ^ j;
                if (ixj > i) {
                    bool up = (i & k) == 0;
                    unsigned long long a = lds[i], c = lds[ixj];
                    if ((a > c) == up) { lds[i] = c; lds[ixj] = a; }
                }
            }
            __syncthreads();
        }
    }
    for (unsigned i = threadIdx.x; i < n; i += 256u) {
        unsigned long long v = lds[i];
        keys[start + i] = (unsigned)(v >> 32);
        ids[start + i]  = (unsigned)(v & 0xFFFFFFFFu);
    }
}

// K5: head flags -> per-scan-block counts
__global__ __launch_bounds__(256) void k_heads(const unsigned* __restrict__ keys,
                                               unsigned* __restrict__ blockSums) {
    __shared__ unsigned red[256];
    unsigned b = blockIdx.x, t = threadIdx.x;
    unsigned base = b * SCAN_EL + t * 8u;
    unsigned prevk = (base > 0) ? keys[base - 1] : 0u;
    unsigned cnt = 0;
#pragma unroll
    for (int r = 0; r < 8; ++r) {
        unsigned k = keys[base + r];
        cnt += ((base + r) == 0 || k != prevk) ? 1u : 0u;
        prevk = k;
    }
    red[t] = cnt;
    __syncthreads();
    for (int d = 128; d > 0; d >>= 1) {
        if (t < (unsigned)d) red[t] += red[t + d];
        __syncthreads();
    }
    if (t == 0) blockSums[b] = red[0];
}

// K6: exclusive scan of 1024 block sums (single wave); total -> uCount
__global__ void k_scan_sums(unsigned* __restrict__ blockSums,
                            unsigned* __restrict__ uCount) {
    int t = threadIdx.x;              // 0..63
    unsigned local[16];
    unsigned s = 0;
#pragma unroll
    for (int i = 0; i < 16; ++i) { local[i] = blockSums[t * 16 + i]; s += local[i]; }
    unsigned v = s;
    for (int d = 1; d < 64; d <<= 1) {
        unsigned o = __shfl_up(v, d, 64);
        if (t >= d) v += o;
    }
    unsigned run = v - s;
#pragma unroll
    for (int i = 0; i < 16; ++i) { blockSums[t * 16 + i] = run; run += local[i]; }
    if (t == 63) *uCount = run;
}

// K7: fused emit + segment-sum. For each head position, compute its global
// unique index u (block offset + intra-block scan), decode row/col, and walk
// the run (usually length 1) summing edge_attr rows in ascending-id order.
__global__ __launch_bounds__(256) void k_emit_attr(const unsigned* __restrict__ keys,
                                                   const unsigned* __restrict__ ids,
                                                   const float* __restrict__ eattr,
                                                   const unsigned* __restrict__ blockSums,
                                                   float* __restrict__ out) {
    __shared__ unsigned sc[256];
    unsigned b = blockIdx.x, t = threadIdx.x;
    unsigned base = b * SCAN_EL + t * 8u;
    unsigned k[8]; bool h[8];
    unsigned prevk = (base > 0) ? keys[base - 1] : 0u;
    unsigned cnt = 0;
#pragma unroll
    for (int r = 0; r < 8; ++r) {
        k[r] = keys[base + r];
        h[r] = ((base + r) == 0 || k[r] != prevk);
        prevk = k[r];
        cnt += h[r] ? 1u : 0u;
    }
    sc[t] = cnt;
    __syncthreads();
    for (int d = 1; d < 256; d <<= 1) {
        unsigned v = sc[t];
        if (t >= (unsigned)d) v += sc[t - d];
        __syncthreads();
        sc[t] = v;
        __syncthreads();
    }
    unsigned u = blockSums[b] + sc[t] - cnt;   // exclusive prefix of heads
#pragma unroll
    for (int r = 0; r < 8; ++r) {
        if (h[r]) {
            out[OUT_ROW + u] = (float)(k[r] >> 16);
            out[OUT_COL + u] = (float)(k[r] & 0xFFFFu);
            float4 s0 = {0,0,0,0}, s1 = {0,0,0,0}, s2 = {0,0,0,0}, s3 = {0,0,0,0};
            unsigned j = base + r;
            do {
                const float4* ap = (const float4*)(eattr + (size_t)ids[j] * 16u);
                float4 a0 = ap[0], a1 = ap[1], a2 = ap[2], a3 = ap[3];
                s0.x += a0.x; s0.y += a0.y; s0.z += a0.z; s0.w += a0.w;
                s1.x += a1.x; s1.y += a1.y; s1.z += a1.z; s1.w += a1.w;
                s2.x += a2.x; s2.y += a2.y; s2.z += a2.z; s2.w += a2.w;
                s3.x += a3.x; s3.y += a3.y; s3.z += a3.z; s3.w += a3.w;
                ++j;
            } while (j < EE && keys[j] == k[r]);
            float4* op = (float4*)(out + OUT_ATTR + (size_t)u * 16u);
            op[0] = s0; op[1] = s1; op[2] = s2; op[3] = s3;
            ++u;
        }
    }
}

// K8: fill pad slots u in [U, EE): sentinel row/col, zero attrs
__global__ __launch_bounds__(256) void k_pad(const unsigned* __restrict__ uCount,
                                             float* __restrict__ out) {
    unsigned u = blockIdx.x * 256u + threadIdx.x;
    unsigned U = *uCount;
    if (u >= U) {
        out[OUT_ROW + u] = 65536.0f;   // sentinel // Np
        out[OUT_COL + u] = 0.0f;       // sentinel %  Np
        float4 z = {0,0,0,0};
        float4* p = (float4*)(out + OUT_ATTR + (size_t)u * 16u);
        p[0] = z; p[1] = z; p[2] = z; p[3] = z;
    }
}

// K9: 2x2 mean pool of x  (read 256 MiB, write 64 MiB)
__global__ __launch_bounds__(256) void k_pool(const float* __restrict__ x,
                                              float* __restrict__ out) {
    unsigned tid = blockIdx.x * 256u + threadIdx.x;   // NPOOL*64 threads
    unsigned n = tid >> 6, g = tid & 63u;
    const float4* r0 = (const float4*)(x + (size_t)(2 * n) * FF) + 2 * g;
    const float4* r1 = (const float4*)(x + (size_t)(2 * n + 1) * FF) + 2 * g;
    float4 a = r0[0], bq = r0[1], c = r1[0], d = r1[1];
    float4 o;
    o.x = 0.25f * ((a.x + a.y) + (c.x + c.y));
    o.y = 0.25f * ((a.z + a.w) + (c.z + c.w));
    o.z = 0.25f * ((bq.x + bq.y) + (d.x + d.y));
    o.w = 0.25f * ((bq.z + bq.w) + (d.z + d.w));
    ((float4*)(out + OUT_X + (size_t)n * FPOOL))[g] = o;
}

// K10: batch_pooled = batch[::2]
__global__ __launch_bounds__(256) void k_batch(const int* __restrict__ batch,
                                               float* __restrict__ out) {
    unsigned n = blockIdx.x * 256u + threadIdx.x;
    if (n < NPOOL) out[OUT_BATCH + n] = (float)batch[2 * n];
}

extern "C" void kernel_launch(void* const* d_in, const int* in_sizes, int n_in,
                              void* d_out, int out_size, void* d_ws, size_t ws_size,
                              hipStream_t stream) {
    const float* x     = (const float*)d_in[0];
    const float* eattr = (const float*)d_in[1];
    const int*   ei    = (const int*)d_in[2];
    const int*   batch = (const int*)d_in[3];
    float* out = (float*)d_out;

    // Workspace: 2*EE u32 + 9217 u32  ~= 16.8 MB
    unsigned* ws        = (unsigned*)d_ws;
    unsigned* keys      = ws;                 // EE
    unsigned* ids       = ws + EE;            // EE
    unsigned* hist      = ws + 2u * EE;       // NBUCK
    unsigned* cursor    = hist + NBUCK;       // NBUCK
    unsigned* blockSums = cursor + NBUCK;     // SCAN_NB
    unsigned* uCount    = blockSums + SCAN_NB;// 1

    k_zero       <<<NBUCK / 256, 256, 0, stream>>>(hist);
    k_hist       <<<EE / 256, 256, 0, stream>>>(ei, hist);
    k_bucket_scan<<<1, 64, 0, stream>>>(hist, cursor);
    k_scatter    <<<EE / 256, 256, 0, stream>>>(ei, cursor, keys, ids);
    k_bsort      <<<NBUCK, 256, 0, stream>>>(cursor, keys, ids);
    k_heads      <<<SCAN_NB, 256, 0, stream>>>(keys, blockSums);
    k_scan_sums  <<<1, 64, 0, stream>>>(blockSums, uCount);
    k_emit_attr  <<<SCAN_NB, 256, 0, stream>>>(keys, ids, eattr, blockSums, out);
    k_pad        <<<EE / 256, 256, 0, stream>>>(uCount, out);
    k_pool       <<<(NPOOL * 64) / 256, 256, 0, stream>>>(x, out);
    k_batch      <<<NPOOL / 256, 256, 0, stream>>>(batch, out);
}